// Round 22
// baseline (43.839 us; speedup 1.0000x reference)
//
#include <hip/hip_runtime.h>
#include <hip/hip_bf16.h>

// Problem constants (from reference setup_inputs)
#define NB 8192   // batch
#define NH 8      // heads
#define ND 512    // D
#define NO 256    // DO
#define ROWS 16   // batch rows per block (M-tile) -> grid=512, 2 blocks/CU
#define TPB 512   // threads per block (8 waves)

typedef __attribute__((ext_vector_type(8))) short short8;
typedef __attribute__((ext_vector_type(4))) float f32x4;

// W converted to bf16 once per launch (256 KB, L2/L3-resident during GEMM phase)
__device__ __align__(16) ushort g_wb[NO * ND];

__device__ __forceinline__ ushort f2bf(float f) {
    union { float f; unsigned u; } v; v.f = f;
    unsigned u = v.u;
    unsigned r = u + 0x7FFFu + ((u >> 16) & 1u);   // round-to-nearest-even
    return (ushort)(r >> 16);
}

__global__ __launch_bounds__(256) void wcvt_kernel(const float* __restrict__ W) {
    int i = (blockIdx.x * 256 + threadIdx.x) * 4;
    float4 w = *(const float4*)(W + i);
    ushort4 o;
    o.x = f2bf(w.x); o.y = f2bf(w.y); o.z = f2bf(w.z); o.w = f2bf(w.w);
    *(ushort4*)(g_wb + i) = o;
}

__device__ __forceinline__ float swishf(float h) {
    // h * sigmoid(h); overflow-safe: h<<0 -> exp(-h)=inf -> rcp=0 -> -0
    return h * __builtin_amdgcn_rcpf(1.0f + __expf(-h));
}

// __launch_bounds__(512, 4): 4 waves/SIMD min occupancy -> VGPR <= 128 ->
// 2 blocks co-resident per CU -> block A's phase 2 overlaps block B's phase 1.
__global__ __launch_bounds__(TPB, 4) void fused_kernel(
    const float* __restrict__ x, const float* __restrict__ rw,
    const float* __restrict__ gamma, const float* __restrict__ beta,
    const float* __restrict__ mean, const float* __restrict__ var,
    const float* __restrict__ bias, float* __restrict__ out)
{
    // y-tile: ROWS x ND bf16, row pitch 1024 B, XOR-swizzled within row
    __shared__ __align__(16) ushort yl[ROWS * ND];   // 16 KB
    __shared__ float rwl[ROWS * NH];                 // 512 B

    const int tid = threadIdx.x;
    const int b0  = blockIdx.x * ROWS;
    const int d4  = tid & 127;        // d-chunk (float4 index)
    const int rh  = tid >> 7;         // 0..3: thread owns rows rh, rh+4, rh+8, rh+12
    const int d   = d4 * 4;

    // phase-2 wave identity
    const int lane = tid & 63;
    const int wv   = tid >> 6;           // 0..7
    const int n0   = wv * 32;            // 32 output cols per wave (2 N-frags)
    const int lr   = lane & 15;
    const int lk   = (lane >> 4) * 8;

    if (tid < 32)
        ((float4*)rwl)[tid] = ((const float4*)(rw + (size_t)b0 * NH))[tid];

    float4 g4 = *(const float4*)(gamma + d);
    float4 v4 = *(const float4*)(var   + d);
    float4 be = *(const float4*)(beta  + d);
    float4 me = *(const float4*)(mean  + d);
    const float ix = g4.x * rsqrtf(v4.x + 1e-5f);
    const float iy = g4.y * rsqrtf(v4.y + 1e-5f);
    const float iz = g4.z * rsqrtf(v4.z + 1e-5f);
    const float iw = g4.w * rsqrtf(v4.w + 1e-5f);
    const float ox = be.x - me.x * ix;
    const float oy = be.y - me.y * iy;
    const float oz = be.z - me.z * iz;
    const float ow = be.w - me.w * iw;

    __syncthreads();   // rwl visible

    // ---------------- phase 1: BN + swish + head-weighted reduce ----------------
    #pragma unroll
    for (int it = 0; it < 4; ++it) {
        const int rr = rh + it * 4;
        const float* xr = x + (size_t)(b0 + rr) * (NH * ND) + d;
        const float4 w0 = ((const float4*)(rwl + rr * NH))[0];
        const float4 w1 = ((const float4*)(rwl + rr * NH))[1];
        const float whv[NH] = {w0.x, w0.y, w0.z, w0.w, w1.x, w1.y, w1.z, w1.w};

        float ax = 0.f, ay = 0.f, az = 0.f, aw = 0.f;
        #pragma unroll
        for (int h = 0; h < NH; ++h) {
            float4 xa = *(const float4*)(xr + h * ND);
            const float wh = whv[h];
            ax += wh * swishf(xa.x * ix + ox);
            ay += wh * swishf(xa.y * iy + oy);
            az += wh * swishf(xa.z * iz + oz);
            aw += wh * swishf(xa.w * iw + ow);
        }
        const int addr = rr * 1024 + ((d * 2) ^ ((rr & 7) << 4));
        ushort4 o;
        o.x = f2bf(ax); o.y = f2bf(ay); o.z = f2bf(az); o.w = f2bf(aw);
        *(ushort4*)((char*)yl + addr) = o;
    }

    // ---------------- W ring prefetch (depth 4, cols lr / lr+16), pre-barrier ----------------
    const ushort* wp = g_wb + (size_t)(n0 + lr) * ND + lk;
    short8 rb0[4], rb1[4];
    #pragma unroll
    for (int p = 0; p < 4; ++p) {
        rb0[p] = *(const short8*)(wp + p * 32);
        rb1[p] = *(const short8*)(wp + 16 * ND + p * 32);
    }
    __builtin_amdgcn_sched_barrier(0);   // keep the prefetch issued above the barrier
    __syncthreads();

    // ---------------- phase 2: [16 x 512] @ W^T via bf16 MFMA ----------------
    f32x4 acc0 = {0.f,0.f,0.f,0.f};
    f32x4 acc1 = {0.f,0.f,0.f,0.f};

    const char* ylb = (const char*)yl + lr * 1024;
    const int swz = (lr & 7) << 4;

    #pragma unroll
    for (int ks = 0; ks < 16; ++ks) {
        short8 b0 = rb0[ks & 3];
        short8 b1 = rb1[ks & 3];
        if (ks + 4 < 16) {
            rb0[ks & 3] = *(const short8*)(wp + (ks + 4) * 32);
            rb1[ks & 3] = *(const short8*)(wp + 16 * ND + (ks + 4) * 32);
        }
        const int kb = (ks * 32 + lk) * 2;
        short8 a = *(const short8*)(ylb + (kb ^ swz));
        acc0 = __builtin_amdgcn_mfma_f32_16x16x32_bf16(a, b0, acc0, 0, 0, 0);
        acc1 = __builtin_amdgcn_mfma_f32_16x16x32_bf16(a, b1, acc1, 0, 0, 0);
    }

    // epilogue: D layout col = lane&15, row = (lane>>4)*4 + reg
    const int rbase = (lane >> 4) * 4;
    float sw[4];
    #pragma unroll
    for (int q = 0; q < 4; ++q) {
        const float* rp = rwl + (rbase + q) * NH;
        sw[q] = ((rp[0] + rp[1]) + (rp[2] + rp[3])) +
                ((rp[4] + rp[5]) + (rp[6] + rp[7]));
    }
    f32x4 accs[2] = {acc0, acc1};
    #pragma unroll
    for (int nf = 0; nf < 2; ++nf) {
        const int col = n0 + nf * 16 + lr;
        const float bn = bias[col];
        #pragma unroll
        for (int q = 0; q < 4; ++q) {
            const int r = rbase + q;
            out[(size_t)(b0 + r) * NO + col] = accs[nf][q] + bn * sw[q];
        }
    }
}

extern "C" void kernel_launch(void* const* d_in, const int* in_sizes, int n_in,
                              void* d_out, int out_size, void* d_ws, size_t ws_size,
                              hipStream_t stream) {
    const float* x     = (const float*)d_in[0];
    const float* rw    = (const float*)d_in[1];
    const float* gamma = (const float*)d_in[2];
    const float* beta  = (const float*)d_in[3];
    const float* mean  = (const float*)d_in[4];
    const float* var   = (const float*)d_in[5];
    const float* W     = (const float*)d_in[6];
    const float* bias  = (const float*)d_in[7];
    float* out = (float*)d_out;

    hipLaunchKernelGGL(wcvt_kernel, dim3((NO * ND) / 1024), dim3(256), 0, stream, W);
    hipLaunchKernelGGL(fused_kernel, dim3(NB / ROWS), dim3(TPB), 0, stream,
                       x, rw, gamma, beta, mean, var, bias, out);
}

// Round 25
// 37.836 us; speedup vs baseline: 1.1586x; 1.1586x over previous
//
#include <hip/hip_runtime.h>
#include <hip/hip_bf16.h>

// Problem constants (from reference setup_inputs)
#define NB 8192   // batch
#define NH 8      // heads
#define ND 512    // D
#define NO 256    // DO
#define ROWS 32   // batch rows per block (M-tile)
#define TPB 1024  // threads per block (16 waves)

typedef __attribute__((ext_vector_type(8))) short short8;
typedef __attribute__((ext_vector_type(4))) float f32x4;

// W converted to bf16 once per launch (256 KB, L2-resident during GEMM phase)
__device__ __align__(16) ushort g_wb[NO * ND];

__device__ __forceinline__ ushort f2bf(float f) {
    union { float f; unsigned u; } v; v.f = f;
    unsigned u = v.u;
    unsigned r = u + 0x7FFFu + ((u >> 16) & 1u);   // round-to-nearest-even
    return (ushort)(r >> 16);
}

__global__ __launch_bounds__(256) void wcvt_kernel(const float* __restrict__ W) {
    int i = (blockIdx.x * 256 + threadIdx.x) * 4;
    float4 w = *(const float4*)(W + i);
    ushort4 o;
    o.x = f2bf(w.x); o.y = f2bf(w.y); o.z = f2bf(w.z); o.w = f2bf(w.w);
    *(ushort4*)(g_wb + i) = o;
}

__device__ __forceinline__ float swishf(float h) {
    // h * sigmoid(h); overflow-safe: h<<0 -> exp(-h)=inf -> rcp=0 -> -0
    return h * __builtin_amdgcn_rcpf(1.0f + __expf(-h));
}

__global__ __launch_bounds__(TPB) void fused_kernel(
    const float* __restrict__ x, const float* __restrict__ rw,
    const float* __restrict__ gamma, const float* __restrict__ beta,
    const float* __restrict__ mean, const float* __restrict__ var,
    const float* __restrict__ bias, float* __restrict__ out)
{
    // y-tile: ROWS x ND bf16, row pitch 1024 B, XOR-swizzled within row
    __shared__ __align__(16) ushort yl[ROWS * ND];   // 32 KB
    __shared__ float rwl[ROWS * NH];                 // 1 KB

    const int tid = threadIdx.x;
    const int b0  = blockIdx.x * ROWS;
    const int d4  = tid & 127;        // d-chunk (float4 index)
    const int rh  = tid >> 7;         // 0..7: thread owns rows rh, rh+8, rh+16, rh+24
    const int d   = d4 * 4;

    // phase-2 wave identity (needed early for the W ring prefetch)
    const int lane = tid & 63;
    const int wv   = tid >> 6;           // 0..15
    const int n0   = wv * 16;            // 16 output cols per wave
    const int lr   = lane & 15;
    const int lk   = (lane >> 4) * 8;

    if (tid < 64)
        ((float4*)rwl)[tid] = ((const float4*)(rw + (size_t)b0 * NH))[tid];

    float4 g4 = *(const float4*)(gamma + d);
    float4 v4 = *(const float4*)(var   + d);
    float4 be = *(const float4*)(beta  + d);
    float4 me = *(const float4*)(mean  + d);
    const float ix = g4.x * rsqrtf(v4.x + 1e-5f);
    const float iy = g4.y * rsqrtf(v4.y + 1e-5f);
    const float iz = g4.z * rsqrtf(v4.z + 1e-5f);
    const float iw = g4.w * rsqrtf(v4.w + 1e-5f);
    const float ox = be.x - me.x * ix;
    const float oy = be.y - me.y * iy;
    const float oz = be.z - me.z * iz;
    const float ow = be.w - me.w * iw;

    __syncthreads();   // rwl visible

    // ---------------- phase 1: BN + swish + head-weighted reduce ----------------
    // 16 waves in flight: 2x outstanding-load capacity vs TPB=512.
    #pragma unroll
    for (int it = 0; it < 4; ++it) {
        const int rr = rh + it * 8;
        const float* xr = x + (size_t)(b0 + rr) * (NH * ND) + d;
        const float4 w0 = ((const float4*)(rwl + rr * NH))[0];
        const float4 w1 = ((const float4*)(rwl + rr * NH))[1];
        const float whv[NH] = {w0.x, w0.y, w0.z, w0.w, w1.x, w1.y, w1.z, w1.w};

        float ax = 0.f, ay = 0.f, az = 0.f, aw = 0.f;
        #pragma unroll
        for (int h = 0; h < NH; ++h) {
            float4 xa = *(const float4*)(xr + h * ND);
            const float wh = whv[h];
            ax += wh * swishf(xa.x * ix + ox);
            ay += wh * swishf(xa.y * iy + oy);
            az += wh * swishf(xa.z * iz + oz);
            aw += wh * swishf(xa.w * iw + ow);
        }
        const int addr = rr * 1024 + ((d * 2) ^ ((rr & 7) << 4));
        ushort4 o;
        o.x = f2bf(ax); o.y = f2bf(ay); o.z = f2bf(az); o.w = f2bf(aw);
        *(ushort4*)((char*)yl + addr) = o;
    }

    // ---------------- W ring prefetch (depth 4) from g_wb, issued pre-barrier ----------------
    // 4 short8 = 16 VGPRs; compile-time indexed under full unroll.
    const ushort* wp = g_wb + (size_t)(n0 + lr) * ND + lk;
    short8 rb[4];
    #pragma unroll
    for (int p = 0; p < 4; ++p)
        rb[p] = *(const short8*)(wp + p * 32);
    __builtin_amdgcn_sched_barrier(0);   // keep the prefetch issued above the barrier
    __syncthreads();

    // ---------------- phase 2: [32 x 512] @ W^T via bf16 MFMA ----------------
    // 16 waves x 16 cols: 2 M-frags x 1 N-frag, 32 MFMAs/wave.
    f32x4 acc0 = {0.f,0.f,0.f,0.f};      // rows 0-15
    f32x4 acc1 = {0.f,0.f,0.f,0.f};      // rows 16-31

    const char* ylb0 = (const char*)yl + lr * 1024;
    const char* ylb1 = (const char*)yl + (lr + 16) * 1024;
    const int swz = (lr & 7) << 4;       // (lr+16)&7 == lr&7: same swizzle both frags

    #pragma unroll
    for (int ks = 0; ks < 16; ++ks) {
        short8 b = rb[ks & 3];
        if (ks + 4 < 16)
            rb[ks & 3] = *(const short8*)(wp + (ks + 4) * 32);
        const int kb = (ks * 32 + lk) * 2;
        short8 a0 = *(const short8*)(ylb0 + (kb ^ swz));
        short8 a1 = *(const short8*)(ylb1 + (kb ^ swz));
        acc0 = __builtin_amdgcn_mfma_f32_16x16x32_bf16(a0, b, acc0, 0, 0, 0);
        acc1 = __builtin_amdgcn_mfma_f32_16x16x32_bf16(a1, b, acc1, 0, 0, 0);
    }

    // epilogue: D layout col = lane&15, row = (lane>>4)*4 + reg (+16 for M-frag 1)
    const int rbase = (lane >> 4) * 4;
    float sw0[4], sw1[4];
    #pragma unroll
    for (int q = 0; q < 4; ++q) {
        const float* rp0 = rwl + (rbase + q) * NH;
        const float* rp1 = rwl + (16 + rbase + q) * NH;
        sw0[q] = ((rp0[0]+rp0[1]) + (rp0[2]+rp0[3])) + ((rp0[4]+rp0[5]) + (rp0[6]+rp0[7]));
        sw1[q] = ((rp1[0]+rp1[1]) + (rp1[2]+rp1[3])) + ((rp1[4]+rp1[5]) + (rp1[6]+rp1[7]));
    }
    const int col = n0 + lr;
    const float bn = bias[col];
    #pragma unroll
    for (int q = 0; q < 4; ++q) {
        const int r = rbase + q;
        out[(size_t)(b0 + r) * NO + col]      = acc0[q] + bn * sw0[q];
        out[(size_t)(b0 + 16 + r) * NO + col] = acc1[q] + bn * sw1[q];
    }
}

extern "C" void kernel_launch(void* const* d_in, const int* in_sizes, int n_in,
                              void* d_out, int out_size, void* d_ws, size_t ws_size,
                              hipStream_t stream) {
    const float* x     = (const float*)d_in[0];
    const float* rw    = (const float*)d_in[1];
    const float* gamma = (const float*)d_in[2];
    const float* beta  = (const float*)d_in[3];
    const float* mean  = (const float*)d_in[4];
    const float* var   = (const float*)d_in[5];
    const float* W     = (const float*)d_in[6];
    const float* bias  = (const float*)d_in[7];
    float* out = (float*)d_out;

    hipLaunchKernelGGL(wcvt_kernel, dim3((NO * ND) / 1024), dim3(256), 0, stream, W);
    hipLaunchKernelGGL(fused_kernel, dim3(NB / ROWS), dim3(TPB), 0, stream,
                       x, rw, gamma, beta, mean, var, bias, out);
}